// Round 2
// baseline (26724.030 us; speedup 1.0000x reference)
//
#include <hip/hip_runtime.h>
#include <math.h>

#define HID  200
#define G4   800          // 4*H
#define BB   16           // batch rows per workgroup
#define NTH  512          // threads per workgroup (8 waves)
#define SEQT 128
#define NOUT 64
#define NHR  1600         // 2 * 800 half-K rows

// ---------------- transpose W (800x200 row-major) -> Wt (200x800) ----------------
__global__ void transpose_all(const float* __restrict__ s0, const float* __restrict__ s1,
                              const float* __restrict__ s2, const float* __restrict__ s3,
                              const float* __restrict__ s4, const float* __restrict__ s5,
                              float* __restrict__ ws) {
    const float* src;
    int m = blockIdx.y;
    switch (m) {
        case 0: src = s0; break;
        case 1: src = s1; break;
        case 2: src = s2; break;
        case 3: src = s3; break;
        case 4: src = s4; break;
        default: src = s5; break;
    }
    float* dst = ws + (size_t)m * (HID * G4);
    int i = blockIdx.x * blockDim.x + threadIdx.x;
    if (i < HID * G4) {
        int k = i / G4;
        int j = i - k * G4;
        dst[i] = src[j * HID + k];   // Wt[k][j] = W[j][k]
    }
}

__device__ __forceinline__ float sigf(float v) { return 1.0f / (1.0f + expf(-v)); }

// accumulate one half-K (100 long) segment of row j into acc[BB]
__device__ __forceinline__ void accum_half(float acc[BB], const float* __restrict__ Wt,
                                           const float* hs, int j, int kb) {
#pragma unroll 2
    for (int kk = 0; kk < 100; kk += 4) {
        const float* w = Wt + (kb + kk) * G4 + j;
        float w0 = w[0];
        float w1 = w[G4];
        float w2 = w[2 * G4];
        float w3 = w[3 * G4];
#pragma unroll
        for (int b = 0; b < BB; ++b) {
            const float4 hv = *reinterpret_cast<const float4*>(hs + b * HID + kb + kk);
            acc[b] = fmaf(hv.x, w0, acc[b]);
            acc[b] = fmaf(hv.y, w1, acc[b]);
            acc[b] = fmaf(hv.z, w2, acc[b]);
            acc[b] = fmaf(hv.w, w3, acc[b]);
        }
    }
}

// cell with scalar input (input dim 1): gates = xin*wih + h@WhhT + bias
__device__ __forceinline__ void cell_matmul_scalar(float* gAbuf, float* gBbuf,
                                                   const float* __restrict__ WhhT,
                                                   const float* hh,
                                                   const float* __restrict__ wih_vec,
                                                   const float* __restrict__ bias,
                                                   const float* xin, int tid) {
#pragma unroll
    for (int r = 0; r < 4; ++r) {
        int hr = tid + r * NTH;
        if (hr < NHR) {
            int half = (hr >= G4) ? 1 : 0;
            int j  = half ? hr - G4 : hr;
            int kb = half ? 100 : 0;
            float acc[BB];
            if (!half) {
                float bj = bias[j];
                float wj = wih_vec[j];
#pragma unroll
                for (int b = 0; b < BB; ++b) acc[b] = fmaf(xin[b], wj, bj);
            } else {
#pragma unroll
                for (int b = 0; b < BB; ++b) acc[b] = 0.0f;
            }
            accum_half(acc, WhhT, hh, j, kb);
            float* g = half ? gBbuf : gAbuf;
#pragma unroll
            for (int b = 0; b < BB; ++b) g[b * G4 + j] = acc[b];
        }
    }
}

// cell with vector input (input dim H): gates = hx@WihT + hh@WhhT + bias
__device__ __forceinline__ void cell_matmul_vec(float* gAbuf, float* gBbuf,
                                                const float* __restrict__ WihT,
                                                const float* hx,
                                                const float* __restrict__ WhhT,
                                                const float* hh,
                                                const float* __restrict__ bias, int tid) {
#pragma unroll
    for (int r = 0; r < 4; ++r) {
        int hr = tid + r * NTH;
        if (hr < NHR) {
            int half = (hr >= G4) ? 1 : 0;
            int j  = half ? hr - G4 : hr;
            int kb = half ? 100 : 0;
            float acc[BB];
            float init = half ? 0.0f : bias[j];
#pragma unroll
            for (int b = 0; b < BB; ++b) acc[b] = init;
            accum_half(acc, WihT, hx, j, kb);
            accum_half(acc, WhhT, hh, j, kb);
            float* g = half ? gBbuf : gAbuf;
#pragma unroll
            for (int b = 0; b < BB; ++b) g[b * G4 + j] = acc[b];
        }
    }
}

__device__ __forceinline__ void cell_elementwise(const float* gA, const float* gB,
                                                 float* hs, float* cs, int tid) {
    for (int i = tid; i < BB * HID; i += NTH) {
        int b = i / HID;
        int m = i - b * HID;
        const float* ga = gA + b * G4;
        const float* gb = gB + b * G4;
        float gi = ga[m]           + gb[m];
        float gf = ga[HID + m]     + gb[HID + m];
        float gg = ga[2 * HID + m] + gb[2 * HID + m];
        float go = ga[3 * HID + m] + gb[3 * HID + m];
        float cp = cs[i];
        float cn = sigf(gf) * cp + sigf(gi) * tanhf(gg);
        cs[i] = cn;
        hs[i] = sigf(go) * tanhf(cn);
    }
}

__global__ __launch_bounds__(NTH)
void lstm_main(const float* __restrict__ x,
               const float* __restrict__ eWih0, const float* __restrict__ eB0,
               const float* __restrict__ eB1,
               const float* __restrict__ dWih0, const float* __restrict__ dB0,
               const float* __restrict__ dB1,
               const float* __restrict__ linW, const float* __restrict__ linb,
               const float* __restrict__ wsT,
               float* __restrict__ out) {
    extern __shared__ float sm[];
    float* gA    = sm;                       // [BB][G4]
    float* gB    = gA + BB * G4;             // [BB][G4]
    float* h1s   = gB + BB * G4;             // [BB][HID]
    float* c1s   = h1s + BB * HID;
    float* h2s   = c1s + BB * HID;
    float* c2s   = h2s + BB * HID;
    float* linWs = c2s + BB * HID;           // [HID]
    float* xb    = linWs + HID;              // [BB]
    float* predb = xb + BB;                  // [BB]
    float* part  = predb + BB;               // [BB][4]

    const float* eWhh0T = wsT;
    const float* eWih1T = wsT + 160000;
    const float* eWhh1T = wsT + 320000;
    const float* dWhh0T = wsT + 480000;
    const float* dWih1T = wsT + 640000;
    const float* dWhh1T = wsT + 800000;

    const int tid = threadIdx.x;
    const int b0g = blockIdx.x * BB;

    for (int i = tid; i < BB * HID; i += NTH) {
        h1s[i] = 0.0f; c1s[i] = 0.0f; h2s[i] = 0.0f; c2s[i] = 0.0f;
    }
    for (int i = tid; i < HID; i += NTH) linWs[i] = linW[i];
    __syncthreads();

    // ---------------- encoder: 128 steps, 2 fused layers ----------------
    for (int t = 0; t < SEQT; ++t) {
        if (tid < BB) xb[tid] = x[(size_t)(b0g + tid) * SEQT + t];
        __syncthreads();
        cell_matmul_scalar(gA, gB, eWhh0T, h1s, eWih0, eB0, xb, tid);
        __syncthreads();
        cell_elementwise(gA, gB, h1s, c1s, tid);
        __syncthreads();
        cell_matmul_vec(gA, gB, eWih1T, h1s, eWhh1T, h2s, eB1, tid);
        __syncthreads();
        cell_elementwise(gA, gB, h2s, c2s, tid);
        __syncthreads();
    }

    if (tid < BB) predb[tid] = x[(size_t)(b0g + tid) * SEQT + (SEQT - 1)];
    __syncthreads();

    // ---------------- decoder: 64 steps with feedback ----------------
    for (int s = 0; s < NOUT; ++s) {
        cell_matmul_scalar(gA, gB, dWhh0T, h1s, dWih0, dB0, predb, tid);
        __syncthreads();
        cell_elementwise(gA, gB, h1s, c1s, tid);
        __syncthreads();
        cell_matmul_vec(gA, gB, dWih1T, h1s, dWhh1T, h2s, dB1, tid);
        __syncthreads();
        cell_elementwise(gA, gB, h2s, c2s, tid);
        __syncthreads();
        if (tid < 64) {
            int b = tid >> 2, q = tid & 3;
            const float* hb = h2s + b * HID + q * 50;
            const float* lw = linWs + q * 50;
            float p = 0.0f;
#pragma unroll 10
            for (int k = 0; k < 50; ++k) p = fmaf(hb[k], lw[k], p);
            part[b * 4 + q] = p;
        }
        __syncthreads();
        if (tid < BB) {
            float p = part[tid * 4] + part[tid * 4 + 1] + part[tid * 4 + 2] + part[tid * 4 + 3] + linb[0];
            predb[tid] = p;
            out[(size_t)(b0g + tid) * NOUT + s] = p;
        }
        __syncthreads();
    }
}

extern "C" void kernel_launch(void* const* d_in, const int* in_sizes, int n_in,
                              void* d_out, int out_size, void* d_ws, size_t ws_size,
                              hipStream_t stream) {
    const float* x     = (const float*)d_in[0];
    const float* eWih0 = (const float*)d_in[1];
    const float* eWhh0 = (const float*)d_in[2];
    const float* eB0   = (const float*)d_in[3];
    const float* eWih1 = (const float*)d_in[4];
    const float* eWhh1 = (const float*)d_in[5];
    const float* eB1   = (const float*)d_in[6];
    const float* dWih0 = (const float*)d_in[7];
    const float* dWhh0 = (const float*)d_in[8];
    const float* dB0   = (const float*)d_in[9];
    const float* dWih1 = (const float*)d_in[10];
    const float* dWhh1 = (const float*)d_in[11];
    const float* dB1   = (const float*)d_in[12];
    const float* linW  = (const float*)d_in[13];
    const float* linb  = (const float*)d_in[14];
    float* ws  = (float*)d_ws;
    float* out = (float*)d_out;

    // 6 transposed matrices into workspace (3.84 MB)
    transpose_all<<<dim3((HID * G4 + 255) / 256, 6), 256, 0, stream>>>(
        eWhh0, eWih1, eWhh1, dWhh0, dWih1, dWhh1, ws);

    size_t smem = (size_t)(2 * BB * G4 + 4 * BB * HID + HID + BB + BB + BB * 4) * sizeof(float);
    (void)hipFuncSetAttribute((const void*)lstm_main,
                              hipFuncAttributeMaxDynamicSharedMemorySize, 160 * 1024);
    lstm_main<<<dim3(4096 / BB), dim3(NTH), smem, stream>>>(
        x, eWih0, eB0, eB1, dWih0, dB0, dB1, linW, linb, ws, out);
}

// Round 3
// 10328.358 us; speedup vs baseline: 2.5874x; 2.5874x over previous
//
#include <hip/hip_runtime.h>
#include <math.h>

#define HID   200
#define G4    800
#define BB    16
#define NTH   512
#define SEQT  128
#define NOUT  64
#define WKP   224               // padded K for weights
#define AST   232               // h LDS row stride (ushorts)
#define GST   802               // gates LDS row stride (floats)
#define MATU  (G4 * WKP)        // 179200 ushorts per matrix plane

typedef __attribute__((ext_vector_type(8))) short short8;
typedef __attribute__((ext_vector_type(4))) float f32x4;
typedef unsigned short ushort_t;

// ---- fp32 -> bf16 (RNE) ----
__device__ __forceinline__ unsigned short bf16_rne(float v) {
    unsigned int u = __float_as_uint(v);
    u = u + 0x7FFFu + ((u >> 16) & 1u);
    return (unsigned short)(u >> 16);
}

// ---------------- weight prep: fp32 W[800][200] -> bf16 hi/lo [800][224] ----------------
__global__ void prep_weights(const float* __restrict__ s0, const float* __restrict__ s1,
                             const float* __restrict__ s2, const float* __restrict__ s3,
                             const float* __restrict__ s4, const float* __restrict__ s5,
                             unsigned short* __restrict__ ws) {
    const float* src;
    int m = blockIdx.y;
    switch (m) {
        case 0: src = s0; break;
        case 1: src = s1; break;
        case 2: src = s2; break;
        case 3: src = s3; break;
        case 4: src = s4; break;
        default: src = s5; break;
    }
    int i = blockIdx.x * blockDim.x + threadIdx.x;   // 0 .. MATU-1 (exact grid)
    int n = i / WKP;
    int k = i - n * WKP;
    float v = (k < HID) ? src[n * HID + k] : 0.0f;
    unsigned short hi = bf16_rne(v);
    float rem = v - __uint_as_float(((unsigned int)hi) << 16);
    unsigned short lo = bf16_rne(rem);
    ws[(size_t)(2 * m) * MATU + i]     = hi;
    ws[(size_t)(2 * m + 1) * MATU + i] = lo;
}

// ---- A fragment from LDS: lane holds h[lane&15][c*32 + 8*(lane>>4) .. +7] ----
__device__ __forceinline__ short8 ldA(const unsigned short* h, int lane, int c) {
    return *(const short8*)(h + (lane & 15) * AST + c * 32 + ((lane >> 4) << 3));
}

// ---- one (A_hi,A_lo) x (W_hi,W_lo) pass: 3-term split-bf16 accumulate ----
template<int NT>
__device__ __forceinline__ void mm_pass(const unsigned short* __restrict__ Whi,
                                        const unsigned short* __restrict__ Wlo,
                                        const unsigned short* hhi, const unsigned short* hlo,
                                        int lane, int tile0, f32x4* acc) {
    short8 ahi[7], alo[7];
#pragma unroll
    for (int c = 0; c < 7; ++c) { ahi[c] = ldA(hhi, lane, c); alo[c] = ldA(hlo, lane, c); }
    const int ko   = (lane >> 4) << 3;
    const int nrow = lane & 15;
#pragma unroll
    for (int t = 0; t < NT; ++t) {
        const unsigned short* wp = Whi + (size_t)((tile0 + t) * 16 + nrow) * WKP + ko;
        const unsigned short* wq = Wlo + (size_t)((tile0 + t) * 16 + nrow) * WKP + ko;
#pragma unroll
        for (int c = 0; c < 7; ++c) {
            short8 bhi = *(const short8*)(wp + c * 32);
            short8 blo = *(const short8*)(wq + c * 32);
            acc[t] = __builtin_amdgcn_mfma_f32_16x16x32_bf16(ahi[c], bhi, acc[t], 0, 0, 0);
            acc[t] = __builtin_amdgcn_mfma_f32_16x16x32_bf16(ahi[c], blo, acc[t], 0, 0, 0);
            acc[t] = __builtin_amdgcn_mfma_f32_16x16x32_bf16(alo[c], bhi, acc[t], 0, 0, 0);
        }
    }
}

// ---- cell matmul, scalar input (input dim 1): acc init = bias[n] + x[b]*wih[n] ----
template<int NT>
__device__ __forceinline__ void cell_mm_s(float* gates,
        const unsigned short* Whi, const unsigned short* Wlo,
        const unsigned short* hhi, const unsigned short* hlo,
        const float* __restrict__ bias, const float* __restrict__ wih,
        const float* xcol, int lane, int tile0) {
    f32x4 acc[NT];
    const int nrow = lane & 15;
    const int bg   = (lane >> 4) << 2;
#pragma unroll
    for (int t = 0; t < NT; ++t) {
        int n = (tile0 + t) * 16 + nrow;
        float bj = bias[n], wj = wih[n];
#pragma unroll
        for (int r = 0; r < 4; ++r) acc[t][r] = fmaf(xcol[bg + r], wj, bj);
    }
    mm_pass<NT>(Whi, Wlo, hhi, hlo, lane, tile0, acc);
#pragma unroll
    for (int t = 0; t < NT; ++t) {
        int n = (tile0 + t) * 16 + nrow;
#pragma unroll
        for (int r = 0; r < 4; ++r) gates[(bg + r) * GST + n] = acc[t][r];
    }
}

// ---- cell matmul, vector input (dim 200): gates = hx@WihT + hh@WhhT + bias ----
template<int NT>
__device__ __forceinline__ void cell_mm_v(float* gates,
        const unsigned short* Wihhi, const unsigned short* Wihlo,
        const unsigned short* Whhhi, const unsigned short* Whhlo,
        const unsigned short* hxhi, const unsigned short* hxlo,
        const unsigned short* hhhi, const unsigned short* hhlo,
        const float* __restrict__ bias, int lane, int tile0) {
    f32x4 acc[NT];
    const int nrow = lane & 15;
    const int bg   = (lane >> 4) << 2;
#pragma unroll
    for (int t = 0; t < NT; ++t) {
        float bj = bias[(tile0 + t) * 16 + nrow];
        acc[t] = (f32x4){bj, bj, bj, bj};
    }
    mm_pass<NT>(Wihhi, Wihlo, hxhi, hxlo, lane, tile0, acc);
    mm_pass<NT>(Whhhi, Whhlo, hhhi, hhlo, lane, tile0, acc);
#pragma unroll
    for (int t = 0; t < NT; ++t) {
        int n = (tile0 + t) * 16 + nrow;
#pragma unroll
        for (int r = 0; r < 4; ++r) gates[(bg + r) * GST + n] = acc[t][r];
    }
}

__device__ __forceinline__ float fsig(float v) {
    return __builtin_amdgcn_rcpf(1.0f + __expf(-v));
}
__device__ __forceinline__ float ftanh(float v) {
    // 1 - 2/(e^{2v}+1); exp overflow -> +1, underflow -> -1 (correct limits)
    return 1.0f - 2.0f * __builtin_amdgcn_rcpf(__expf(2.0f * v) + 1.0f);
}

// ---- elementwise: gates -> (c in VGPRs), h -> bf16 hi/lo in LDS ----
__device__ __forceinline__ void cell_ew(const float* gates,
                                        unsigned short* hhi, unsigned short* hlo,
                                        float* cv, int tid) {
#pragma unroll
    for (int r = 0; r < 7; ++r) {
        int i = tid + r * NTH;
        if (i < BB * HID) {
            int b = i / HID;
            int m = i - b * HID;
            const float* g = gates + b * GST;
            float gi = g[m], gf = g[HID + m], gg = g[2 * HID + m], go = g[3 * HID + m];
            float cp = cv[r];
            float cn = fsig(gf) * cp + fsig(gi) * ftanh(gg);
            cv[r] = cn;
            float h = fsig(go) * ftanh(cn);
            unsigned short hb = bf16_rne(h);
            float rem = h - __uint_as_float(((unsigned int)hb) << 16);
            unsigned short lb = bf16_rne(rem);
            hhi[b * AST + m] = hb;
            hlo[b * AST + m] = lb;
        }
    }
}

__global__ __launch_bounds__(NTH, 2)
void lstm_mfma(const float* __restrict__ x,
               const float* __restrict__ eWih0, const float* __restrict__ eB0,
               const float* __restrict__ eB1,
               const float* __restrict__ dWih0, const float* __restrict__ dB0,
               const float* __restrict__ dB1,
               const float* __restrict__ linW, const float* __restrict__ linb,
               const unsigned short* __restrict__ wst,
               float* __restrict__ out) {
    extern __shared__ char smraw[];
    float* gates = (float*)smraw;                       // [BB][GST]
    float* xsT   = gates + BB * GST;                    // [SEQT][BB] transposed
    float* linWs = xsT + SEQT * BB;                     // [HID]
    float* predb = linWs + HID;                         // [BB]
    float* part  = predb + BB;                          // [BB*4]
    unsigned short* h1hi = (unsigned short*)(part + BB * 4);
    unsigned short* h1lo = h1hi + BB * AST;
    unsigned short* h2hi = h1lo + BB * AST;
    unsigned short* h2lo = h2hi + BB * AST;

    const unsigned short* eWhh0hi = wst;
    const unsigned short* eWhh0lo = wst + MATU;
    const unsigned short* eWih1hi = wst + 2 * MATU;
    const unsigned short* eWih1lo = wst + 3 * MATU;
    const unsigned short* eWhh1hi = wst + 4 * MATU;
    const unsigned short* eWhh1lo = wst + 5 * MATU;
    const unsigned short* dWhh0hi = wst + 6 * MATU;
    const unsigned short* dWhh0lo = wst + 7 * MATU;
    const unsigned short* dWih1hi = wst + 8 * MATU;
    const unsigned short* dWih1lo = wst + 9 * MATU;
    const unsigned short* dWhh1hi = wst + 10 * MATU;
    const unsigned short* dWhh1lo = wst + 11 * MATU;

    const int tid  = threadIdx.x;
    const int lane = tid & 63;
    const int w    = tid >> 6;
    const int b0g  = blockIdx.x * BB;
    const int tile0 = (w < 2) ? 7 * w : 14 + 6 * (w - 2);   // waves 0,1: 7 tiles; 2..7: 6 tiles

    for (int i = tid; i < BB * AST; i += NTH) {
        h1hi[i] = 0; h1lo[i] = 0; h2hi[i] = 0; h2lo[i] = 0;
    }
    for (int i = tid; i < BB * SEQT; i += NTH) {
        int b = i >> 7, t = i & (SEQT - 1);
        xsT[t * BB + b] = x[(size_t)(b0g + b) * SEQT + t];
    }
    for (int i = tid; i < HID; i += NTH) linWs[i] = linW[i];
    float c1v[7], c2v[7];
#pragma unroll
    for (int r = 0; r < 7; ++r) { c1v[r] = 0.0f; c2v[r] = 0.0f; }
    __syncthreads();

    // ---------------- encoder: 128 steps, 2 fused layers ----------------
    for (int t = 0; t < SEQT; ++t) {
        const float* xcol = xsT + t * BB;
        if (w < 2) cell_mm_s<7>(gates, eWhh0hi, eWhh0lo, h1hi, h1lo, eB0, eWih0, xcol, lane, tile0);
        else       cell_mm_s<6>(gates, eWhh0hi, eWhh0lo, h1hi, h1lo, eB0, eWih0, xcol, lane, tile0);
        __syncthreads();
        cell_ew(gates, h1hi, h1lo, c1v, tid);
        __syncthreads();
        if (w < 2) cell_mm_v<7>(gates, eWih1hi, eWih1lo, eWhh1hi, eWhh1lo, h1hi, h1lo, h2hi, h2lo, eB1, lane, tile0);
        else       cell_mm_v<6>(gates, eWih1hi, eWih1lo, eWhh1hi, eWhh1lo, h1hi, h1lo, h2hi, h2lo, eB1, lane, tile0);
        __syncthreads();
        cell_ew(gates, h2hi, h2lo, c2v, tid);
        __syncthreads();
    }

    if (tid < BB) predb[tid] = xsT[(SEQT - 1) * BB + tid];
    __syncthreads();

    // ---------------- decoder: 64 steps with feedback ----------------
    for (int s = 0; s < NOUT; ++s) {
        if (w < 2) cell_mm_s<7>(gates, dWhh0hi, dWhh0lo, h1hi, h1lo, dB0, dWih0, predb, lane, tile0);
        else       cell_mm_s<6>(gates, dWhh0hi, dWhh0lo, h1hi, h1lo, dB0, dWih0, predb, lane, tile0);
        __syncthreads();
        cell_ew(gates, h1hi, h1lo, c1v, tid);
        __syncthreads();
        if (w < 2) cell_mm_v<7>(gates, dWih1hi, dWih1lo, dWhh1hi, dWhh1lo, h1hi, h1lo, h2hi, h2lo, dB1, lane, tile0);
        else       cell_mm_v<6>(gates, dWih1hi, dWih1lo, dWhh1hi, dWhh1lo, h1hi, h1lo, h2hi, h2lo, dB1, lane, tile0);
        __syncthreads();
        cell_ew(gates, h2hi, h2lo, c2v, tid);
        __syncthreads();
        if (tid < 64) {
            int b = tid >> 2, q = tid & 3;
            const unsigned short* ph = h2hi + b * AST + q * 50;
            const unsigned short* pl = h2lo + b * AST + q * 50;
            const float* lw = linWs + q * 50;
            float p = 0.0f;
#pragma unroll 10
            for (int k = 0; k < 50; ++k) {
                float hv = __uint_as_float(((unsigned int)ph[k]) << 16)
                         + __uint_as_float(((unsigned int)pl[k]) << 16);
                p = fmaf(hv, lw[k], p);
            }
            part[tid] = p;   // tid = b*4+q
        }
        __syncthreads();
        if (tid < BB) {
            float p = part[tid * 4] + part[tid * 4 + 1] + part[tid * 4 + 2] + part[tid * 4 + 3]
                    + linb[0];
            predb[tid] = p;
            out[(size_t)(b0g + tid) * NOUT + s] = p;
        }
        __syncthreads();
    }
}

extern "C" void kernel_launch(void* const* d_in, const int* in_sizes, int n_in,
                              void* d_out, int out_size, void* d_ws, size_t ws_size,
                              hipStream_t stream) {
    const float* x     = (const float*)d_in[0];
    const float* eWih0 = (const float*)d_in[1];
    const float* eWhh0 = (const float*)d_in[2];
    const float* eB0   = (const float*)d_in[3];
    const float* eWih1 = (const float*)d_in[4];
    const float* eWhh1 = (const float*)d_in[5];
    const float* eB1   = (const float*)d_in[6];
    const float* dWih0 = (const float*)d_in[7];
    const float* dWhh0 = (const float*)d_in[8];
    const float* dB0   = (const float*)d_in[9];
    const float* dWih1 = (const float*)d_in[10];
    const float* dWhh1 = (const float*)d_in[11];
    const float* dB1   = (const float*)d_in[12];
    const float* linW  = (const float*)d_in[13];
    const float* linb  = (const float*)d_in[14];
    unsigned short* ws = (unsigned short*)d_ws;
    float* out = (float*)d_out;

    // bf16 hi/lo split of the 6 big matrices, K padded 200->224 (4.3 MB)
    prep_weights<<<dim3(MATU / 256, 6), 256, 0, stream>>>(
        eWhh0, eWih1, eWhh1, dWhh0, dWih1, dWhh1, ws);

    size_t smem = (size_t)(BB * GST + SEQT * BB + HID + BB + BB * 4) * sizeof(float)
                + (size_t)(4 * BB * AST) * sizeof(unsigned short);
    (void)hipFuncSetAttribute((const void*)lstm_mfma,
                              hipFuncAttributeMaxDynamicSharedMemorySize, 160 * 1024);
    lstm_mfma<<<dim3(4096 / BB), dim3(NTH), smem, stream>>>(
        x, eWih0, eB0, eB1, dWih0, dB0, dB1, linW, linb, ws, out);
}